// Round 14
// baseline (245.921 us; speedup 1.0000x reference)
//
#include <hip/hip_runtime.h>
#include <stdint.h>

#define NN 10000
#define NE 160000
#define MPAD 10112   // 79 * 128 = 158 * 64
#define MTILES 79

typedef unsigned short u16;
typedef float f32x4 __attribute__((ext_vector_type(4)));
typedef short short8 __attribute__((ext_vector_type(8)));
typedef __bf16 bf16x8 __attribute__((ext_vector_type(8)));
typedef unsigned short u16x4 __attribute__((ext_vector_type(4)));
typedef unsigned short u16x8 __attribute__((ext_vector_type(8)));

__device__ __forceinline__ float bf2f(u16 u) {
  union { unsigned u; float f; } c; c.u = ((unsigned)u) << 16; return c.f;
}
__device__ __forceinline__ u16 f2bf(float f) {
  union { float f; unsigned u; } c; c.f = f;
  return (u16)((c.u + 0x7FFFu + ((c.u >> 16) & 1u)) >> 16);
}

__device__ __forceinline__ void gld_lds16(void* lds, const void* g) {
  __builtin_amdgcn_global_load_lds(
      (const unsigned int __attribute__((address_space(1)))*)g,
      (unsigned int __attribute__((address_space(3)))*)lds, 16, 0, 0);
}

// ---------------- CSR build ----------------
__global__ __launch_bounds__(256) void deg_count(const int* __restrict__ dst, int* __restrict__ deg) {
  int e = blockIdx.x * 256 + threadIdx.x;
  if (e < NE) atomicAdd(&deg[dst[e]], 1);
}

// LDS-staged scan: coalesced global loads -> LDS, scan in LDS, coalesced flush.
__global__ __launch_bounds__(256) void scan_off(const int* __restrict__ deg,
                                                int* __restrict__ roff, int* __restrict__ cur) {
  __shared__ int sdeg[10240];        // 40 KB
  __shared__ int part[256];
  const int t = threadIdx.x;
  for (int k = t; k < NN; k += 256) sdeg[k] = deg[k];
  for (int k = NN + t; k < 10240; k += 256) sdeg[k] = 0;   // pad
  __syncthreads();
  const int CH = 40;
  int s = 0;
#pragma unroll
  for (int i = 0; i < CH; ++i) s += sdeg[t * CH + i];
  part[t] = s; __syncthreads();
  for (int off = 1; off < 256; off <<= 1) {
    int v = (t >= off) ? part[t - off] : 0;
    __syncthreads(); part[t] += v; __syncthreads();
  }
  int run = (t == 0) ? 0 : part[t - 1];
#pragma unroll
  for (int i = 0; i < CH; ++i) {
    const int idx = t * CH + i;
    const int d = sdeg[idx];
    sdeg[idx] = run;                 // exclusive prefix in place
    run += d;
  }
  __syncthreads();
  for (int k = t; k < NN; k += 256) { const int v = sdeg[k]; roff[k] = v; cur[k] = v; }
  if (t == 255) roff[NN] = NE;
}

// ---------------- conversions ----------------
// Also zeroes deg[] (first 40 blocks) - replaces the hipMemsetAsync dispatch.
__global__ __launch_bounds__(256) void convert_h(const float* __restrict__ h, u16* __restrict__ hbf,
                                                 int* __restrict__ deg) {
  if (blockIdx.x < 40) {
    const int z = blockIdx.x * 256 + threadIdx.x;
    if (z < NN) deg[z] = 0;
  }
  const size_t i = (size_t)(blockIdx.x * 256 + threadIdx.x) * 4;
  if (i >= (size_t)MPAD * 960) return;
  u16x4 o;
  if (i < (size_t)NN * 960) {
    float4 v = *(const float4*)(h + i);
    o[0] = f2bf(v.x); o[1] = f2bf(v.y); o[2] = f2bf(v.z); o[3] = f2bf(v.w);
  } else {
    o[0] = 0; o[1] = 0; o[2] = 0; o[3] = 0;
  }
  *(u16x4*)(hbf + i) = o;
}

// weight transposes: out[c*ldo + r] = bf16(in[r][c]); z==7 slice runs
// fill_csr (scan_off has completed before this launch; transpose slices are
// independent of CSR data, so co-launch is safe).
struct WDesc { const float* in; u16* out; int R, C, Cpad, ldo, koff; };
struct WPack { WDesc d[7]; const int* src; const int* dst; int* cur; int* esrc; };

__global__ __launch_bounds__(256) void transpose_all(WPack p) {
  if (blockIdx.z == 7) {             // fused fill_csr
    int e = (blockIdx.y * 32 + blockIdx.x) * 256 + threadIdx.x;
    if (e < NE) {
      int pos = atomicAdd(&p.cur[p.dst[e]], 1);
      p.esrc[pos] = p.src[e];
    }
    return;
  }
  const WDesc w = p.d[blockIdx.z];
  const int cb = blockIdx.x * 32, rb = blockIdx.y * 32;
  if (cb >= w.Cpad || rb >= w.R) return;
  __shared__ float tile[32][33];
  const int tx = threadIdx.x & 31, ty = threadIdx.x >> 5;
  for (int i = ty; i < 32; i += 8) {
    int r = rb + i, c = cb + tx;
    tile[i][tx] = (r < w.R && c < w.C) ? w.in[(size_t)r * w.C + c] : 0.f;
  }
  __syncthreads();
  for (int i = ty; i < 32; i += 8) {
    int c = cb + i, r = rb + tx;
    if (c < w.Cpad && r < w.R) w.out[(size_t)c * w.ldo + w.koff + r] = f2bf(tile[tx][i]);
  }
}

// ---------------- GEMM: outputs = act(A @ B^T + bias [+ Cin]) ----------------
// STAGING LAW (rounds 0-11): time == per-CU staged bytes / rate(b);
// rate ~9-13 B/cy at 1.2 blocks/CU, ~19-20 at 2.4 (LDS caps residency at 2).
// Total staged bytes are near-minimal at TM=TN=128; the remaining lever is
// moving bytes from low-rate (small-grid) gemms into high-rate ones.
// ROUND 14: N-concat split. The s/n projections are computed as extra
// N-columns of the PRECEDING gemm (high b), with the f32 partial parked in
// Cf; the aggregate-dependent gemm then runs at HALF K and adds Cin.
// Epilogue: tn < nsplit -> bf16 out (bias, act, ldcb) [+ Cin];
//           tn >= nsplit -> f32 out to Cf (no bias, no act).
// Same f32 sums regrouped => exact to ~ulp (partials stored f32).
// K-loop = round-5 verbatim (the family optimum): 8 waves, BK=64, two 32KB
// buffers, per phase: vmcnt(NC); barrier; ds_read; lgkmcnt(0); barrier;
// stage t+2 into same buffer; MFMA x16. Swizzle: phys slot = logical ^
// (row&7) on both pre-swizzled global source and ds_read (rule #21).
// Known non-levers (do not retry): NSTG=4, TM/TN=64, BK changes,
// reg-staging at <256-reg budget, dual-path staging.
template<int TM, int TN, int MINW>
__global__ __launch_bounds__(512, MINW) void gemm3(
    const u16* __restrict__ A0, int lda0,
    const u16* __restrict__ A1, int lda1, int ksplit,
    const u16* __restrict__ B,
    const float* __restrict__ bias, int nbias,
    u16* __restrict__ Cb, int ldcb,
    float* __restrict__ Cf, int ldcf, int nsplit,
    const float* __restrict__ Cin, int ldcin,
    int K, int act, int tiles_n) {
  constexpr int TR = TM + TN;        // staged rows per K-tile (256)
  constexpr int NC = TR * 128 / (512 * 16);  // gld instrs per lane per stage (4)
  constexpr int WCOLS = 4;           // 8 waves: 2 rows x 4 cols
  constexpr int WN = TN / WCOLS;     // 32
  constexpr int NJ = WN / 16;        // 2
  constexpr int MT = MPAD / TM;      // M tiles
  __shared__ __align__(16) u16 S0[TR * 64];
  __shared__ __align__(16) u16 S1[TR * 64];
  const int tid = threadIdx.x;
  const int wave = tid >> 6, lane = tid & 63;

  // bijective XCD-chunked swizzle over col-fastest linear id (m204)
  const int nwg = tiles_n * MT;
  const int orig = blockIdx.x + blockIdx.y * tiles_n;
  const int q = nwg >> 3, r8 = nwg & 7;
  const int xcd = orig & 7, idx = orig >> 3;
  const int wg = (xcd < r8 ? xcd * (q + 1) : r8 * (q + 1) + (xcd - r8) * q) + idx;
  const int tm = (wg / tiles_n) * TM;
  const int tn = (wg % tiles_n) * TN;

  const int wr = (wave / WCOLS) * 64;
  const int wc = (wave % WCOLS) * WN;
  const int fr = lane & 15, fq = lane >> 4;
  const int sr8 = lane >> 3;         // row within 8-row wave chunk
  const int sslot = lane & 7;        // 16B slot within 128B row
  f32x4 acc[4][NJ] = {};

  auto stage = [&](u16* Sw, int kk) {
#pragma unroll
    for (int c = 0; c < NC; ++c) {
      const int row = c * 64 + wave * 8 + sr8;                // LDS row
      const int gs = (sslot ^ (row & 7)) * 8;                 // pre-swizzled k-slot
      const void* g;
      if (c < NC * TM / TR) {                                 // A rows (row < TM)
        g = (kk < ksplit)
            ? (const void*)&A0[(size_t)(tm + row) * lda0 + kk + gs]
            : (const void*)&A1[(size_t)(tm + row) * lda1 + (kk - ksplit) + gs];
      } else {                                                // B rows
        g = (const void*)&B[(size_t)(tn + row - TM) * (size_t)K + kk + gs];
      }
      gld_lds16(&Sw[(c * 64 + wave * 8) * 64], g);            // wave-uniform base
    }
  };

  const int nsteps = K >> 6;          // BK=64; all K used are multiples of 64
  stage(S0, 0);
  stage(S1, 64);
  for (int base = 0; base < nsteps; base += 2) {
#pragma unroll
    for (int ph = 0; ph < 2; ++ph) {
      const int t = base + ph;
      if (t >= nsteps) break;
      u16* Sr = (ph == 0) ? S0 : S1;   // holds tile t; also gets tile t+2
      if (t + 1 < nsteps) {
        asm volatile("s_waitcnt vmcnt(%0)" :: "i"(NC) : "memory");  // tile t landed
      } else {
        asm volatile("s_waitcnt vmcnt(0)" ::: "memory");
      }
      __builtin_amdgcn_s_barrier();    // all waves' parts of tile t landed
      __builtin_amdgcn_sched_barrier(0);
      short8 af[4][2], bfr[2][NJ];
#pragma unroll
      for (int i = 0; i < 4; ++i) {
        const int r = wr + i * 16 + fr;
#pragma unroll
        for (int kc = 0; kc < 2; ++kc)
          af[i][kc] = *(const short8*)&Sr[r * 64 + ((((kc << 2) | fq) ^ (r & 7)) << 3)];
      }
#pragma unroll
      for (int j = 0; j < NJ; ++j) {
        const int r = TM + wc + j * 16 + fr;
#pragma unroll
        for (int kc = 0; kc < 2; ++kc)
          bfr[kc][j] = *(const short8*)&Sr[r * 64 + ((((kc << 2) | fq) ^ (r & 7)) << 3)];
      }
      asm volatile("s_waitcnt lgkmcnt(0)" ::: "memory");  // frags in registers
      __builtin_amdgcn_sched_barrier(0);
      __builtin_amdgcn_s_barrier();    // ALL waves done reading Sr -> safe to overwrite
      if (t + 2 < nsteps) stage(Sr, (t + 2) << 6);
      __builtin_amdgcn_s_setprio(1);
#pragma unroll
      for (int kc = 0; kc < 2; ++kc)
#pragma unroll
        for (int i = 0; i < 4; ++i)
#pragma unroll
          for (int j = 0; j < NJ; ++j)
            acc[i][j] = __builtin_amdgcn_mfma_f32_16x16x32_bf16(
                __builtin_bit_cast(bf16x8, af[i][kc]), __builtin_bit_cast(bf16x8, bfr[kc][j]),
                acc[i][j], 0, 0, 0);
      __builtin_amdgcn_s_setprio(0);
      __builtin_amdgcn_sched_barrier(0);
    }
  }

  // C/D layout: col=lane&15, row=(lane>>4)*4+reg (m89/m91 verified)
  const int cr = fq * 4, cc = fr;
  if (tn < nsplit) {                   // bf16 output region (bias, act, [+Cin])
#pragma unroll
    for (int i = 0; i < 4; ++i)
#pragma unroll
      for (int j = 0; j < NJ; ++j) {
        const int col = tn + wc + j * 16 + cc;
        const float bv = (col < nbias) ? bias[col] : 0.f;
#pragma unroll
        for (int r = 0; r < 4; ++r) {
          const int row = tm + wr + i * 16 + cr + r;
          float v = acc[i][j][r] + bv;
          if (Cin) v += Cin[(size_t)row * ldcin + col];
          if (act) v = fmaxf(v, 0.f);
          Cb[(size_t)row * ldcb + col] = f2bf(v);
        }
      }
  } else {                             // f32 partial region (no bias/act)
#pragma unroll
    for (int i = 0; i < 4; ++i)
#pragma unroll
      for (int j = 0; j < NJ; ++j) {
        const int col = tn - nsplit + wc + j * 16 + cc;
#pragma unroll
        for (int r = 0; r < 4; ++r) {
          const int row = tm + wr + i * 16 + cr + r;
          Cf[(size_t)row * ldcf + col] = acc[i][j][r];
        }
      }
  }
}

// ---------------- segment max, XCD feature-sliced ----------------
template<int CW>
__global__ __launch_bounds__(256) void aggregate_xcd(
    const u16* __restrict__ m, int ldm, const int* __restrict__ roff,
    const int* __restrict__ esrc, u16* __restrict__ neigh, int ldn) {
  constexpr int TPN = CW / 8;          // threads per node
  constexpr int NPB = 256 / TPN;       // nodes per block
  const int chunk = blockIdx.x & 7;
  const int node = (blockIdx.x >> 3) * NPB + threadIdx.x / TPN;
  if (node >= NN) return;
  const int fi = chunk * CW + (threadIdx.x % TPN) * 8;
  const int beg = roff[node], end = roff[node + 1];
  u16x8 a;
#pragma unroll
  for (int i = 0; i < 8; ++i) a[i] = 0;
  for (int e = beg; e < end; ++e) {
    const u16* row = m + (size_t)esrc[e] * ldm;
    u16x8 v = *(const u16x8*)(row + fi);
#pragma unroll
    for (int i = 0; i < 8; ++i) a[i] = (v[i] > a[i]) ? v[i] : a[i];
  }
  *(u16x8*)(neigh + (size_t)node * ldn + fi) = a;
}

// ---------------- layer 2 fused: aggregate + sigmoid(x2.Ws2 + neigh.Wn2 + b2) ----
__global__ __launch_bounds__(256) void agg_final(
    const u16* __restrict__ m, const int* __restrict__ roff,
    const int* __restrict__ esrc, const u16* __restrict__ x,
    const float* __restrict__ ws, const float* __restrict__ wn,
    const float* __restrict__ b, float* __restrict__ out) {
  const int wave = threadIdx.x >> 6, lane = threadIdx.x & 63;
  const int n = blockIdx.x * 4 + wave;
  if (n >= NN) return;
  const int f = lane * 8;
  const int beg = roff[n], end = roff[n + 1];
  u16x8 a;
#pragma unroll
  for (int i = 0; i < 8; ++i) a[i] = 0;
  for (int e = beg; e < end; ++e) {
    u16x8 v = *(const u16x8*)(m + (size_t)esrc[e] * 512 + f);
#pragma unroll
    for (int i = 0; i < 8; ++i) a[i] = (v[i] > a[i]) ? v[i] : a[i];
  }
  const u16x8 xv = *(const u16x8*)(x + (size_t)n * 512 + f);
  float s = 0.f;
#pragma unroll
  for (int i = 0; i < 8; ++i)
    s += bf2f(xv[i]) * ws[f + i] + bf2f(a[i]) * wn[f + i];
#pragma unroll
  for (int o = 32; o > 0; o >>= 1) s += __shfl_xor(s, o);
  if (lane == 0) out[n] = 1.f / (1.f + expf(-(s + b[0])));
}

extern "C" void kernel_launch(void* const* d_in, const int* in_sizes, int n_in,
                              void* d_out, int out_size, void* d_ws, size_t ws_size,
                              hipStream_t stream) {
  const float* h   = (const float*)d_in[0];
  const int*   src = (const int*)d_in[1];
  const int*   dst = (const int*)d_in[2];
  const float* Wp0 = (const float*)d_in[3];
  const float* bp0 = (const float*)d_in[4];
  const float* Ws0 = (const float*)d_in[5];
  const float* Wn0 = (const float*)d_in[6];
  const float* b0  = (const float*)d_in[7];
  const float* Wp1 = (const float*)d_in[8];
  const float* bp1 = (const float*)d_in[9];
  const float* Ws1 = (const float*)d_in[10];
  const float* Wn1 = (const float*)d_in[11];
  const float* b1  = (const float*)d_in[12];
  const float* Wp2 = (const float*)d_in[13];
  const float* bp2 = (const float*)d_in[14];
  const float* Ws2 = (const float*)d_in[15];
  const float* Wn2 = (const float*)d_in[16];
  const float* b2  = (const float*)d_in[17];
  float* out = (float*)d_out;

  char* ws = (char*)d_ws;
  size_t off = 0;
  auto alloc = [&](size_t n) { char* p = ws + off; off = (off + n + 255) & ~(size_t)255; return p; };
  u16* hbf   = (u16*)alloc((size_t)MPAD * 960 * 2);
  u16* x1    = (u16*)alloc((size_t)MPAD * 512 * 2);
  u16* x2    = (u16*)alloc((size_t)MPAD * 512 * 2);
  u16* mbuf  = (u16*)alloc((size_t)MPAD * 1024 * 2);
  u16* nbuf  = (u16*)alloc((size_t)MPAD * 1024 * 2);
  float* xa0 = (float*)alloc((size_t)MPAD * 512 * 4);  // f32 partial hbf@Ws0
  float* xa1 = (float*)alloc((size_t)MPAD * 512 * 4);  // f32 partial x1@Ws1
  u16* Wcat0 = (u16*)alloc((size_t)1536 * 960 * 2);    // [Wp0T(1024) ; Ws0T(512)] rows, K=960
  u16* WnT0  = (u16*)alloc((size_t)512 * 960 * 2);
  u16* Wcat1 = (u16*)alloc((size_t)1024 * 512 * 2);    // [Wp1T(512) ; Ws1T(512)]
  u16* WnT1  = (u16*)alloc((size_t)512 * 512 * 2);
  u16* WpT2  = (u16*)alloc((size_t)512 * 512 * 2);
  int* deg   = (int*)alloc(NN * 4);
  int* roff  = (int*)alloc((NN + 1) * 4);
  int* curp  = (int*)alloc(NN * 4);
  int* esrc  = (int*)alloc(NE * 4);

  convert_h<<<(MPAD * 960 / 4) / 256, 256, 0, stream>>>(h, hbf, deg);  // also zeroes deg
  deg_count<<<NE / 256, 256, 0, stream>>>(dst, deg);
  scan_off<<<1, 256, 0, stream>>>(deg, roff, curp);

  WPack wp;
  wp.d[0] = {Wp0, Wcat0,              960, 960, 1024, 960, 0};
  wp.d[1] = {Ws0, Wcat0 + 1024 * 960, 960, 512,  512, 960, 0};
  wp.d[2] = {Wn0, WnT0,               960, 512,  512, 960, 0};
  wp.d[3] = {Wp1, Wcat1,              512, 512,  512, 512, 0};
  wp.d[4] = {Ws1, Wcat1 + 512 * 512,  512, 512,  512, 512, 0};
  wp.d[5] = {Wn1, WnT1,               512, 512,  512, 512, 0};
  wp.d[6] = {Wp2, WpT2,               512, 512,  512, 512, 0};
  wp.src = src; wp.dst = dst; wp.cur = curp; wp.esrc = esrc;
  transpose_all<<<dim3(32, 30, 8), 256, 0, stream>>>(wp);  // z==7 runs fill_csr

  // ---- layer 0 ----
  // G1': [mbuf(1024,relu) | xa0(512,f32)] = hbf @ [Wp0T|Ws0T], K=960, N=1536
  gemm3<128, 128, 4><<<dim3(12, 79), 512, 0, stream>>>(
      hbf, 960, hbf, 960, 960, Wcat0, bp0, 960,
      mbuf, 1024, xa0, 512, 1024, nullptr, 0, 960, 1, 12);
  aggregate_xcd<128><<<5000, 256, 0, stream>>>(mbuf, 1024, roff, esrc, nbuf, 1024);
  // G2': x1 = relu(nbuf @ Wn0T + xa0 + b0), K=960
  gemm3<128, 128, 4><<<dim3(4, 79), 512, 0, stream>>>(
      nbuf, 1024, nbuf, 1024, 960, WnT0, b0, 512,
      x1, 512, nullptr, 0, 512, xa0, 512, 960, 1, 4);

  // ---- layer 1 ----
  // G3': [mbuf(512,relu) | xa1(512,f32)] = x1 @ [Wp1T|Ws1T], K=512, N=1024
  gemm3<128, 128, 4><<<dim3(8, 79), 512, 0, stream>>>(
      x1, 512, x1, 512, 512, Wcat1, bp1, 512,
      mbuf, 512, xa1, 512, 512, nullptr, 0, 512, 1, 8);
  aggregate_xcd<64><<<2504, 256, 0, stream>>>(mbuf, 512, roff, esrc, nbuf, 512);
  // G4': x2 = relu(nbuf @ Wn1T + xa1 + b1), K=512
  gemm3<128, 128, 4><<<dim3(4, 79), 512, 0, stream>>>(
      nbuf, 512, nbuf, 512, 512, WnT1, b1, 512,
      x2, 512, nullptr, 0, 512, xa1, 512, 512, 1, 4);

  // ---- layer 2 ----
  gemm3<128, 128, 4><<<dim3(4, 79), 512, 0, stream>>>(
      x2, 512, x2, 512, 512, WpT2, bp2, 512,
      mbuf, 512, nullptr, 0, 512, nullptr, 0, 512, 1, 4);
  agg_final<<<2500, 256, 0, stream>>>(mbuf, roff, esrc, x2, Ws2, Wn2, b2, out);
}

// Round 15
// 226.370 us; speedup vs baseline: 1.0864x; 1.0864x over previous
//
#include <hip/hip_runtime.h>
#include <stdint.h>

#define NN 10000
#define NE 160000
#define MPAD 10112   // 79 * 128 = 158 * 64
#define MTILES 79

typedef unsigned short u16;
typedef float f32x4 __attribute__((ext_vector_type(4)));
typedef short short8 __attribute__((ext_vector_type(8)));
typedef __bf16 bf16x8 __attribute__((ext_vector_type(8)));
typedef unsigned short u16x4 __attribute__((ext_vector_type(4)));
typedef unsigned short u16x8 __attribute__((ext_vector_type(8)));

__device__ __forceinline__ float bf2f(u16 u) {
  union { unsigned u; float f; } c; c.u = ((unsigned)u) << 16; return c.f;
}
__device__ __forceinline__ u16 f2bf(float f) {
  union { float f; unsigned u; } c; c.f = f;
  return (u16)((c.u + 0x7FFFu + ((c.u >> 16) & 1u)) >> 16);
}

__device__ __forceinline__ void gld_lds16(void* lds, const void* g) {
  __builtin_amdgcn_global_load_lds(
      (const unsigned int __attribute__((address_space(1)))*)g,
      (unsigned int __attribute__((address_space(3)))*)lds, 16, 0, 0);
}

// ---------------- CSR build ----------------
__global__ __launch_bounds__(256) void deg_count(const int* __restrict__ dst, int* __restrict__ deg) {
  int e = blockIdx.x * 256 + threadIdx.x;
  if (e < NE) atomicAdd(&deg[dst[e]], 1);
}

// LDS-staged scan: coalesced global loads -> LDS, scan in LDS, coalesced flush.
__global__ __launch_bounds__(256) void scan_off(const int* __restrict__ deg,
                                                int* __restrict__ roff, int* __restrict__ cur) {
  __shared__ int sdeg[10240];        // 40 KB
  __shared__ int part[256];
  const int t = threadIdx.x;
  for (int k = t; k < NN; k += 256) sdeg[k] = deg[k];
  for (int k = NN + t; k < 10240; k += 256) sdeg[k] = 0;   // pad
  __syncthreads();
  const int CH = 40;
  int s = 0;
#pragma unroll
  for (int i = 0; i < CH; ++i) s += sdeg[t * CH + i];
  part[t] = s; __syncthreads();
  for (int off = 1; off < 256; off <<= 1) {
    int v = (t >= off) ? part[t - off] : 0;
    __syncthreads(); part[t] += v; __syncthreads();
  }
  int run = (t == 0) ? 0 : part[t - 1];
#pragma unroll
  for (int i = 0; i < CH; ++i) {
    const int idx = t * CH + i;
    const int d = sdeg[idx];
    sdeg[idx] = run;                 // exclusive prefix in place
    run += d;
  }
  __syncthreads();
  for (int k = t; k < NN; k += 256) { const int v = sdeg[k]; roff[k] = v; cur[k] = v; }
  if (t == 255) roff[NN] = NE;
}

// ---------------- conversions ----------------
// Also zeroes deg[] (first 40 blocks) - replaces the hipMemsetAsync dispatch.
__global__ __launch_bounds__(256) void convert_h(const float* __restrict__ h, u16* __restrict__ hbf,
                                                 int* __restrict__ deg) {
  if (blockIdx.x < 40) {
    const int z = blockIdx.x * 256 + threadIdx.x;
    if (z < NN) deg[z] = 0;
  }
  const size_t i = (size_t)(blockIdx.x * 256 + threadIdx.x) * 4;
  if (i >= (size_t)MPAD * 960) return;
  u16x4 o;
  if (i < (size_t)NN * 960) {
    float4 v = *(const float4*)(h + i);
    o[0] = f2bf(v.x); o[1] = f2bf(v.y); o[2] = f2bf(v.z); o[3] = f2bf(v.w);
  } else {
    o[0] = 0; o[1] = 0; o[2] = 0; o[3] = 0;
  }
  *(u16x4*)(hbf + i) = o;
}

// weight transposes, K-concat capable: out[c*ldo + koff + r] = bf16(in[r][c]);
// z==7 slice runs fill_csr (scan_off completed before this launch; the
// transpose slices are independent of CSR data, so co-launch is safe).
struct WDesc { const float* in; u16* out; int R, C, Cpad, ldo, koff; };
struct WPack { WDesc d[7]; const int* src; const int* dst; int* cur; int* esrc; };

__global__ __launch_bounds__(256) void transpose_all(WPack p) {
  if (blockIdx.z == 7) {             // fused fill_csr
    int e = (blockIdx.y * 32 + blockIdx.x) * 256 + threadIdx.x;
    if (e < NE) {
      int pos = atomicAdd(&p.cur[p.dst[e]], 1);
      p.esrc[pos] = p.src[e];
    }
    return;
  }
  const WDesc w = p.d[blockIdx.z];
  const int cb = blockIdx.x * 32, rb = blockIdx.y * 32;
  if (cb >= w.Cpad || rb >= w.R) return;
  __shared__ float tile[32][33];
  const int tx = threadIdx.x & 31, ty = threadIdx.x >> 5;
  for (int i = ty; i < 32; i += 8) {
    int r = rb + i, c = cb + tx;
    tile[i][tx] = (r < w.R && c < w.C) ? w.in[(size_t)r * w.C + c] : 0.f;
  }
  __syncthreads();
  for (int i = ty; i < 32; i += 8) {
    int c = cb + i, r = rb + tx;
    if (c < w.Cpad && r < w.R) w.out[(size_t)c * w.ldo + w.koff + r] = f2bf(tile[tx][i]);
  }
}

// ---------------- GEMM: Cb = act(([A0|A1]) @ B^T + bias) ----------------
// STAGING LAW (rounds 0-14): K-loop time == one block's serial phase chain;
// per-CU staging rate ~9-13 B/cy at 1.2 blocks/CU, ~19-20 at 2.4; byte x
// rate product flat across tile shape (r2/r11), BK (r3), depth (r1), wave
// count (r5), staging path (r4/r6-r10). EPILOGUE bytes are coalescing-
// sensitive and OUTSIDE the law: r14's f32-partial N-concat kept the
// K-loops flat but lost ~17us to scattered f32 partial write+read.
// This file = round-13 config, the measured optimum (228.7us):
// 8-WAVE blocks (512 thr), BK=64, two 32KB buffers, per phase:
//   vmcnt(NC) [tile t landed; t+1 in flight] ; s_barrier ; ds_read tile t ;
//   lgkmcnt(0) ; s_barrier [all waves' frags in regs] ; stage tile t+2
//   into the same buffer ; MFMA (16/wave).
// Swizzle (8x16B slots per 128B row): phys = logical ^ (row&7), same XOR
// on the pre-swizzled global source (rule #21, involution). ksplit%64==0.
// Known non-levers (do not retry): NSTG=4, TM/TN=64, BK changes,
// reg-staging at <256-reg budget, dual-path staging, f32-partial N-concat.
template<int TM, int TN, int MINW>
__global__ __launch_bounds__(512, MINW) void gemm3(
    const u16* __restrict__ A0, int lda0,
    const u16* __restrict__ A1, int lda1, int ksplit,
    const u16* __restrict__ B,
    const float* __restrict__ bias, int nbias,
    u16* __restrict__ Cb, int ldcb,
    int K, int act, int tiles_n) {
  constexpr int TR = TM + TN;        // staged rows per K-tile (256)
  constexpr int NC = TR * 128 / (512 * 16);  // gld instrs per lane per stage (4)
  constexpr int WCOLS = 4;           // 8 waves: 2 rows x 4 cols
  constexpr int WN = TN / WCOLS;     // 32
  constexpr int NJ = WN / 16;        // 2
  constexpr int MT = MPAD / TM;      // M tiles
  __shared__ __align__(16) u16 S0[TR * 64];
  __shared__ __align__(16) u16 S1[TR * 64];
  const int tid = threadIdx.x;
  const int wave = tid >> 6, lane = tid & 63;

  // bijective XCD-chunked swizzle over col-fastest linear id (m204)
  const int nwg = tiles_n * MT;
  const int orig = blockIdx.x + blockIdx.y * tiles_n;
  const int q = nwg >> 3, r8 = nwg & 7;
  const int xcd = orig & 7, idx = orig >> 3;
  const int wg = (xcd < r8 ? xcd * (q + 1) : r8 * (q + 1) + (xcd - r8) * q) + idx;
  const int tm = (wg / tiles_n) * TM;
  const int tn = (wg % tiles_n) * TN;

  const int wr = (wave / WCOLS) * 64;
  const int wc = (wave % WCOLS) * WN;
  const int fr = lane & 15, fq = lane >> 4;
  const int sr8 = lane >> 3;         // row within 8-row wave chunk
  const int sslot = lane & 7;        // 16B slot within 128B row
  f32x4 acc[4][NJ] = {};

  auto stage = [&](u16* Sw, int kk) {
#pragma unroll
    for (int c = 0; c < NC; ++c) {
      const int row = c * 64 + wave * 8 + sr8;                // LDS row
      const int gs = (sslot ^ (row & 7)) * 8;                 // pre-swizzled k-slot
      const void* g;
      if (c < NC * TM / TR) {                                 // A rows (row < TM)
        g = (kk < ksplit)
            ? (const void*)&A0[(size_t)(tm + row) * lda0 + kk + gs]
            : (const void*)&A1[(size_t)(tm + row) * lda1 + (kk - ksplit) + gs];
      } else {                                                // B rows
        g = (const void*)&B[(size_t)(tn + row - TM) * (size_t)K + kk + gs];
      }
      gld_lds16(&Sw[(c * 64 + wave * 8) * 64], g);            // wave-uniform base
    }
  };

  const int nsteps = K >> 6;          // BK=64; all K used are multiples of 64
  stage(S0, 0);
  stage(S1, 64);
  for (int base = 0; base < nsteps; base += 2) {
#pragma unroll
    for (int ph = 0; ph < 2; ++ph) {
      const int t = base + ph;
      if (t >= nsteps) break;
      u16* Sr = (ph == 0) ? S0 : S1;   // holds tile t; also gets tile t+2
      if (t + 1 < nsteps) {
        asm volatile("s_waitcnt vmcnt(%0)" :: "i"(NC) : "memory");  // tile t landed
      } else {
        asm volatile("s_waitcnt vmcnt(0)" ::: "memory");
      }
      __builtin_amdgcn_s_barrier();    // all waves' parts of tile t landed
      __builtin_amdgcn_sched_barrier(0);
      short8 af[4][2], bfr[2][NJ];
#pragma unroll
      for (int i = 0; i < 4; ++i) {
        const int r = wr + i * 16 + fr;
#pragma unroll
        for (int kc = 0; kc < 2; ++kc)
          af[i][kc] = *(const short8*)&Sr[r * 64 + ((((kc << 2) | fq) ^ (r & 7)) << 3)];
      }
#pragma unroll
      for (int j = 0; j < NJ; ++j) {
        const int r = TM + wc + j * 16 + fr;
#pragma unroll
        for (int kc = 0; kc < 2; ++kc)
          bfr[kc][j] = *(const short8*)&Sr[r * 64 + ((((kc << 2) | fq) ^ (r & 7)) << 3)];
      }
      asm volatile("s_waitcnt lgkmcnt(0)" ::: "memory");  // frags in registers
      __builtin_amdgcn_sched_barrier(0);
      __builtin_amdgcn_s_barrier();    // ALL waves done reading Sr -> safe to overwrite
      if (t + 2 < nsteps) stage(Sr, (t + 2) << 6);
      __builtin_amdgcn_s_setprio(1);
#pragma unroll
      for (int kc = 0; kc < 2; ++kc)
#pragma unroll
        for (int i = 0; i < 4; ++i)
#pragma unroll
          for (int j = 0; j < NJ; ++j)
            acc[i][j] = __builtin_amdgcn_mfma_f32_16x16x32_bf16(
                __builtin_bit_cast(bf16x8, af[i][kc]), __builtin_bit_cast(bf16x8, bfr[kc][j]),
                acc[i][j], 0, 0, 0);
      __builtin_amdgcn_s_setprio(0);
      __builtin_amdgcn_sched_barrier(0);
    }
  }

  // C/D layout: col=lane&15, row=(lane>>4)*4+reg (m89/m91 verified)
  const int cr = fq * 4, cc = fr;
#pragma unroll
  for (int i = 0; i < 4; ++i)
#pragma unroll
    for (int j = 0; j < NJ; ++j) {
      const int col = tn + wc + j * 16 + cc;
      const float bv = (col < nbias) ? bias[col] : 0.f;
#pragma unroll
      for (int r = 0; r < 4; ++r) {
        const int row = tm + wr + i * 16 + cr + r;
        float v = acc[i][j][r] + bv;
        if (act) v = fmaxf(v, 0.f);
        Cb[(size_t)row * ldcb + col] = f2bf(v);
      }
    }
}

// ---------------- segment max, XCD feature-sliced ----------------
// Feature dim split into 8 slices of CW; slice c pinned to XCD c via
// blockIdx.x & 7. Per-XCD working set MPAD*CW*2B = 2.6MB/1.3MB < 4MB L2.
// relu'd bf16 >= 0: u16 compare == float compare; 0 == empty-segment fill.
template<int CW>
__global__ __launch_bounds__(256) void aggregate_xcd(
    const u16* __restrict__ m, int ldm, const int* __restrict__ roff,
    const int* __restrict__ esrc, u16* __restrict__ neigh, int ldn) {
  constexpr int TPN = CW / 8;          // threads per node
  constexpr int NPB = 256 / TPN;       // nodes per block
  const int chunk = blockIdx.x & 7;
  const int node = (blockIdx.x >> 3) * NPB + threadIdx.x / TPN;
  if (node >= NN) return;
  const int fi = chunk * CW + (threadIdx.x % TPN) * 8;
  const int beg = roff[node], end = roff[node + 1];
  u16x8 a;
#pragma unroll
  for (int i = 0; i < 8; ++i) a[i] = 0;
  for (int e = beg; e < end; ++e) {
    const u16* row = m + (size_t)esrc[e] * ldm;
    u16x8 v = *(const u16x8*)(row + fi);
#pragma unroll
    for (int i = 0; i < 8; ++i) a[i] = (v[i] > a[i]) ? v[i] : a[i];
  }
  *(u16x8*)(neigh + (size_t)node * ldn + fi) = a;
}

// ---------------- layer 2 fused: aggregate + sigmoid(x2.Ws2 + neigh.Wn2 + b2) ----
// One wave per node: 64 lanes x 8 features hold the segment-max in
// registers (from mbuf, ld=512), then the two dot products + wave reduce.
__global__ __launch_bounds__(256) void agg_final(
    const u16* __restrict__ m, const int* __restrict__ roff,
    const int* __restrict__ esrc, const u16* __restrict__ x,
    const float* __restrict__ ws, const float* __restrict__ wn,
    const float* __restrict__ b, float* __restrict__ out) {
  const int wave = threadIdx.x >> 6, lane = threadIdx.x & 63;
  const int n = blockIdx.x * 4 + wave;
  if (n >= NN) return;
  const int f = lane * 8;
  const int beg = roff[n], end = roff[n + 1];
  u16x8 a;
#pragma unroll
  for (int i = 0; i < 8; ++i) a[i] = 0;
  for (int e = beg; e < end; ++e) {
    u16x8 v = *(const u16x8*)(m + (size_t)esrc[e] * 512 + f);
#pragma unroll
    for (int i = 0; i < 8; ++i) a[i] = (v[i] > a[i]) ? v[i] : a[i];
  }
  const u16x8 xv = *(const u16x8*)(x + (size_t)n * 512 + f);
  float s = 0.f;
#pragma unroll
  for (int i = 0; i < 8; ++i)
    s += bf2f(xv[i]) * ws[f + i] + bf2f(a[i]) * wn[f + i];
#pragma unroll
  for (int o = 32; o > 0; o >>= 1) s += __shfl_xor(s, o);
  if (lane == 0) out[n] = 1.f / (1.f + expf(-(s + b[0])));
}

extern "C" void kernel_launch(void* const* d_in, const int* in_sizes, int n_in,
                              void* d_out, int out_size, void* d_ws, size_t ws_size,
                              hipStream_t stream) {
  const float* h   = (const float*)d_in[0];
  const int*   src = (const int*)d_in[1];
  const int*   dst = (const int*)d_in[2];
  const float* Wp0 = (const float*)d_in[3];
  const float* bp0 = (const float*)d_in[4];
  const float* Ws0 = (const float*)d_in[5];
  const float* Wn0 = (const float*)d_in[6];
  const float* b0  = (const float*)d_in[7];
  const float* Wp1 = (const float*)d_in[8];
  const float* bp1 = (const float*)d_in[9];
  const float* Ws1 = (const float*)d_in[10];
  const float* Wn1 = (const float*)d_in[11];
  const float* b1  = (const float*)d_in[12];
  const float* Wp2 = (const float*)d_in[13];
  const float* bp2 = (const float*)d_in[14];
  const float* Ws2 = (const float*)d_in[15];
  const float* Wn2 = (const float*)d_in[16];
  const float* b2  = (const float*)d_in[17];
  float* out = (float*)d_out;

  char* ws = (char*)d_ws;
  size_t off = 0;
  auto alloc = [&](size_t n) { char* p = ws + off; off = (off + n + 255) & ~(size_t)255; return p; };
  u16* hbf   = (u16*)alloc((size_t)MPAD * 960 * 2);
  u16* x1    = (u16*)alloc((size_t)MPAD * 512 * 2);
  u16* x2    = (u16*)alloc((size_t)MPAD * 512 * 2);
  u16* mbuf  = (u16*)alloc((size_t)MPAD * 1024 * 2);
  u16* nbuf  = (u16*)alloc((size_t)MPAD * 1024 * 2);
  u16* WpT0  = (u16*)alloc((size_t)1024 * 960 * 2);   // [1024 cols][K=960]
  u16* Bcat0 = (u16*)alloc((size_t)512 * 1920 * 2);   // [512][Ws0(960) ; Wn0(960)]
  u16* WpT1  = (u16*)alloc((size_t)512 * 512 * 2);
  u16* Bcat1 = (u16*)alloc((size_t)512 * 1024 * 2);   // [512][Ws1(512) ; Wn1(512)]
  u16* WpT2  = (u16*)alloc((size_t)512 * 512 * 2);
  int* deg   = (int*)alloc(NN * 4);
  int* roff  = (int*)alloc((NN + 1) * 4);
  int* curp  = (int*)alloc(NN * 4);
  int* esrc  = (int*)alloc(NE * 4);

  convert_h<<<(MPAD * 960 / 4) / 256, 256, 0, stream>>>(h, hbf, deg);  // also zeroes deg
  deg_count<<<NE / 256, 256, 0, stream>>>(dst, deg);
  scan_off<<<1, 256, 0, stream>>>(deg, roff, curp);

  WPack wp;
  wp.d[0] = {Wp0, WpT0,  960, 960, 1024,  960,   0};
  wp.d[1] = {Ws0, Bcat0, 960, 512,  512, 1920,   0};
  wp.d[2] = {Wn0, Bcat0, 960, 512,  512, 1920, 960};
  wp.d[3] = {Wp1, WpT1,  512, 512,  512,  512,   0};
  wp.d[4] = {Ws1, Bcat1, 512, 512,  512, 1024,   0};
  wp.d[5] = {Wn1, Bcat1, 512, 512,  512, 1024, 512};
  wp.d[6] = {Wp2, WpT2,  512, 512,  512,  512,   0};
  wp.src = src; wp.dst = dst; wp.cur = curp; wp.esrc = esrc;
  transpose_all<<<dim3(32, 30, 8), 256, 0, stream>>>(wp);  // z==7 runs fill_csr

  // ---- layer 0 (960 -> 512) ----
  // G1: m0 = relu(hbf @ Wp0 + bp0)  [N=1024 padded, 960 real]
  gemm3<128, 128, 4><<<dim3(8, 79), 512, 0, stream>>>(
      hbf, 960, hbf, 960, 960, WpT0, bp0, 960, mbuf, 1024, 960, 1, 8);
  aggregate_xcd<128><<<5000, 256, 0, stream>>>(mbuf, 1024, roff, esrc, nbuf, 1024);
  // G2: x1 = relu([hbf | nbuf] @ [Ws0;Wn0] + b0)  K = 1920
  gemm3<128, 128, 4><<<dim3(4, 79), 512, 0, stream>>>(
      hbf, 960, nbuf, 1024, 960, Bcat0, b0, 512, x1, 512, 1920, 1, 4);

  // ---- layer 1 (512 -> 512) ----
  gemm3<128, 128, 4><<<dim3(4, 79), 512, 0, stream>>>(
      x1, 512, x1, 512, 512, WpT1, bp1, 512, mbuf, 512, 512, 1, 4);
  aggregate_xcd<64><<<2504, 256, 0, stream>>>(mbuf, 512, roff, esrc, nbuf, 512);
  gemm3<128, 128, 4><<<dim3(4, 79), 512, 0, stream>>>(
      x1, 512, nbuf, 512, 512, Bcat1, b1, 512, x2, 512, 1024, 1, 4);

  // ---- layer 2 (512 -> 1) ----
  gemm3<128, 128, 4><<<dim3(4, 79), 512, 0, stream>>>(
      x2, 512, x2, 512, 512, WpT2, bp2, 512, mbuf, 512, 512, 1, 4);
  agg_final<<<2500, 256, 0, stream>>>(mbuf, roff, esrc, x2, Ws2, Wn2, b2, out);
}